// Round 3
// baseline (2784.077 us; speedup 1.0000x reference)
//
#include <hip/hip_runtime.h>
#include <math.h>

#define TPB 1024   // 16 waves = 4/SIMD; thread = (freq = tid>>1, half = tid&1)
                   // PAIR LAYOUT: the two section-halves of a frequency are
                   // ADJACENT LANES -> L-exchange is one quad_perm DPP add,
                   // no Lpart LDS round-trip (2 barriers/iter).

typedef float v2f __attribute__((ext_vector_type(2)));

// Compiler-generated packed math only — NO hand-written v_pk_* asm (R5/R7).
static __device__ __forceinline__ v2f fma2(v2f a, v2f b, v2f c) {
    return __builtin_elementwise_fma(a, b, c);
}
static __device__ __forceinline__ float rcp_nr(float x) {
    float r = __builtin_amdgcn_rcpf(x);
    return r * fmaf(-x, r, 2.0f);
}
// RAW v_rcp_f32 (~1 ulp): NR step dropped (R16). Perturbation absorbed like
// the R4/R8/R12 reorders (absmax stayed 8-16x under threshold, contracting).
static __device__ __forceinline__ v2f rcp2(v2f x) {
    v2f r;
    r.x = __builtin_amdgcn_rcpf(x.x);
    r.y = __builtin_amdgcn_rcpf(x.y);
    return r;
}

// Both lanes of an even/odd pair get the pair total (commutative add ->
// bit-identical K on both lanes). s_nop 1 covers VALU->DPP hazard.
static __device__ __forceinline__ float pair_sum(float L) {
    asm("s_nop 1\n\t"
        "v_add_f32 %0, %0, %0 quad_perm:[1,0,3,2] row_mask:0xf bank_mask:0xf bound_ctrl:0"
        : "+v"(L));
    return L;
}

// Six independent HALF-AWARE 4-freq reductions: stage 1 = stride-2 add
// (combines the 2 same-half freqs of a quad), stage 2 = stride-4 add.
// Lanes (tid&7)==6 (half0) and ==7 (half1) hold the 4-freq group sums.
// Round-robin gives 6-inst spacing; s_nop 1 covers the entry hazard.
__device__ __forceinline__ void red6_g8(float i0, float i1, float i2,
                                        float i3, float i4, float i5,
                                        float& o0, float& o1, float& o2,
                                        float& o3, float& o4, float& o5) {
    asm("s_nop 1\n\t"
        "v_add_f32 %0, %6, %6  row_shr:2 row_mask:0xf bank_mask:0xf bound_ctrl:0\n\t"
        "v_add_f32 %3, %9, %9  row_shr:2 row_mask:0xf bank_mask:0xf bound_ctrl:0\n\t"
        "v_add_f32 %1, %7, %7  row_shr:2 row_mask:0xf bank_mask:0xf bound_ctrl:0\n\t"
        "v_add_f32 %4, %10, %10 row_shr:2 row_mask:0xf bank_mask:0xf bound_ctrl:0\n\t"
        "v_add_f32 %2, %8, %8  row_shr:2 row_mask:0xf bank_mask:0xf bound_ctrl:0\n\t"
        "v_add_f32 %5, %11, %11 row_shr:2 row_mask:0xf bank_mask:0xf bound_ctrl:0\n\t"
        "v_add_f32 %0, %0, %0 row_shr:4 row_mask:0xf bank_mask:0xf bound_ctrl:0\n\t"
        "v_add_f32 %3, %3, %3 row_shr:4 row_mask:0xf bank_mask:0xf bound_ctrl:0\n\t"
        "v_add_f32 %1, %1, %1 row_shr:4 row_mask:0xf bank_mask:0xf bound_ctrl:0\n\t"
        "v_add_f32 %4, %4, %4 row_shr:4 row_mask:0xf bank_mask:0xf bound_ctrl:0\n\t"
        "v_add_f32 %2, %2, %2 row_shr:4 row_mask:0xf bank_mask:0xf bound_ctrl:0\n\t"
        "v_add_f32 %5, %5, %5 row_shr:4 row_mask:0xf bank_mask:0xf bound_ctrl:0"
        : "=&v"(o0), "=&v"(o1), "=&v"(o2), "=&v"(o3), "=&v"(o4), "=&v"(o5)
        : "v"(i0), "v"(i1), "v"(i2), "v"(i3), "v"(i4), "v"(i5));
}

// 8-lane combine for the update stage: lane (tid&7)==7 gets the group sum.
__device__ __forceinline__ float red1_g8(float g) {
    asm("s_nop 1\n\t"
        "v_add_f32 %0, %0, %0 row_shr:1 row_mask:0xf bank_mask:0xf bound_ctrl:0\n\t"
        "s_nop 1\n\t"
        "v_add_f32 %0, %0, %0 row_shr:2 row_mask:0xf bank_mask:0xf bound_ctrl:0\n\t"
        "s_nop 1\n\t"
        "v_add_f32 %0, %0, %0 row_shr:4 row_mask:0xf bank_mask:0xf bound_ctrl:0"
        : "+v"(g));
    return g;
}

// coefficient k (0..5 = b0,b1,b2,a0,a1,a2) -> paired column in
// [b0 a0 b1 a1 b2 a2]: b0,b1,b2 -> 0,2,4 ; a0,a1,a2 -> 1,3,5
__device__ __forceinline__ int cmap(int k) {
    return (k < 3) ? 2 * k : 2 * k - 5;
}

// gpart column layout, MOD-8 BANK-BALANCED (R3): section sec gets 8 cols at
// (sec&7)*8 + 64*(sec>>3); within the block, coefficient k sits at column
// ck[sec&3][k], chosen so every wave of 8 consecutive coefficients has its
// 8 column residues forming a PERMUTATION mod 8 -> ds_read2_b32 banks
// (8*oct + ucol) are provably 2 lanes/bank (the wave64 minimum). Types:
//   ty0: {0,1,2,3,4,5}   ty1: {6,7,0,1,2,3}
//   ty2: {4,5,6,7,0,1}   ty3: {2,3,4,5,6,7}
__device__ __forceinline__ int ckmap(int ty, int k) {
    return (ty == 0) ? k
         : (ty == 1) ? (k < 2 ? k + 6 : k - 2)
         : (ty == 2) ? (k < 4 ? k + 4 : k - 4)
                     : k + 2;
}

// GSTRIDE=132: 132*4=528 ≡ 0 mod 16 (float4 LDS ops must not split, R13);
// 132%32=4 -> writer rows spread start-banks, 2 starts/bank (free).
// !!! ds_read2_b32 offset1:132 in the update asm == GSTRIDE — keep in sync.
#define GSTRIDE 132

__global__
__attribute__((amdgpu_flat_work_group_size(TPB, TPB), amdgpu_waves_per_eu(4, 4)))
void sgd_filter(const float* __restrict__ sos_in,
                const float* __restrict__ target,
                float* __restrict__ out) {
    // 16 sections x 6 floats, PAIRED, NO pad: [b0 a0 b1 a1 b2 a2].
    __shared__ __align__(16) float sos[96];
    // 128 rows (row = tid>>3 = one 4-freq group), 16 sections x 8 cols;
    // half0 sections at cols 0..63, half1 at 64..127 (type-mapped inside).
    __shared__ __align__(16) float gpart[128][GSTRIDE];

    const int tid  = threadIdx.x;
    const int fr   = tid >> 1;     // frequency (lane pairs share it)
    const int half = tid & 1;      // section half: 0 -> s0..7, 1 -> s8..15
    const float* secbase = &sos[half * 48];   // 8 sections x 6 floats

    if (tid < 96) sos[(tid / 6) * 6 + cmap(tid % 6)] = sos_in[tid];

    // Update identity: 8 threads per coefficient u = tid>>3 (tid<768; waves
    // 12..15 skip the whole update phase wave-uniformly).
    const int u    = tid >> 3;
    const int oct  = tid & 7;
    const int usec = u / 6;
    const int uk   = u % 6;
    const int ucol = (usec & 7) * 8 + 64 * (usec >> 3) + ckmap(usec & 3, uk);
    const int uscol = usec * 6 + cmap(uk);        // sos col (paired layout)
    const bool upd = (tid < 768);
    const bool writer = upd && (oct == 7);
    float myc = 0.0f;
    if (writer) myc = sos_in[u];

    // Update-read base addresses, HOISTED out of the 1000-iter loop:
    // thread (u,oct) reads row pairs {2*oct+16*j, +1} of column ucol via
    // ds_read2_b32 (offset1 = +1 row). 8 bases, stride 16 rows = 8448 B.
    const unsigned gb = (unsigned)(uintptr_t)(&gpart[2 * oct][ucol & 127]);
    const unsigned ga0 = gb,            ga1 = gb + 1 * 8448,
                   ga2 = gb + 2 * 8448, ga3 = gb + 3 * 8448,
                   ga4 = gb + 4 * 8448, ga5 = gb + 5 * 8448,
                   ga6 = gb + 6 * 8448, ga7 = gb + 7 * 8448;

    // Per-frequency constants
    const float w  = (float)((double)fr * (3.14159265358979323846 / 511.0));
    const float c1 = cosf(w);
    const float s1 = -sinf(w);           // z1 = e^{-jw}
    const float c2 = c1 * c1 - s1 * s1;  // z2 = z1^2
    const float s2 = 2.0f * c1 * s1;
    const float tgt = target[fr];
    const float KC = 40.0f / (512.0f * 2.302585092994046f); // 40/(n*ln10)

    v2f c1v; c1v.x = c1; c1v.y = c1;
    v2f s1v; s1v.x = s1; s1v.y = s1;
    v2f c2v; c2v.x = c2; c2v.y = c2;
    v2f s2v; s2v.x = s2; s2v.y = s2;

    __syncthreads();

    // 8 sections/thread: Re, Im, 1/n kept (1/n folded into K in backward).
    v2f R0, R1, R2, R3, R4, R5, R6, R7;
    v2f I0, I1, I2, I3, I4, I5, I6, I7;
    v2f V0, V1, V2, V3, V4, V5, V6, V7;

// Two sections per 3 x ds_read_b128 (12 LDS reads/thread vs 16 padded);
// both halves' addresses are 48 floats apart -> disjoint bank sets,
// broadcast within each half: conflict-free.
#define SEC_PAIR(sa, sb)                                                     \
    {                                                                        \
        const float4 q0 = *(const float4*)(secbase + (sa) * 6);              \
        const float4 q1 = *(const float4*)(secbase + (sa) * 6 + 4);          \
        const float4 q2 = *(const float4*)(secbase + (sa) * 6 + 8);          \
        v2f ba0, ba1, ba2;                                                   \
        ba0.x = q0.x; ba0.y = q0.y;                                          \
        ba1.x = q0.z; ba1.y = q0.w;                                          \
        ba2.x = q1.x; ba2.y = q1.y;                                          \
        R##sa = fma2(ba2, c2v, fma2(ba1, c1v, ba0));                         \
        I##sa = fma2(ba2, s2v, ba1 * s1v);                                   \
        {                                                                    \
            const v2f n = fma2(R##sa, R##sa, I##sa * I##sa);                 \
            prod = prod * n;                                                 \
            V##sa = rcp2(n);                                                 \
        }                                                                    \
        ba0.x = q1.z; ba0.y = q1.w;                                          \
        ba1.x = q2.x; ba1.y = q2.y;                                          \
        ba2.x = q2.z; ba2.y = q2.w;                                          \
        R##sb = fma2(ba2, c2v, fma2(ba1, c1v, ba0));                         \
        I##sb = fma2(ba2, s2v, ba1 * s1v);                                   \
        {                                                                    \
            const v2f n = fma2(R##sb, R##sb, I##sb * I##sb);                 \
            prod = prod * n;                                                 \
            V##sb = rcp2(n);                                                 \
        }                                                                    \
    }

// Backward: scale stored directions, 2-stage DPP reduce (4 freqs/group),
// writers = lanes (tid&7)==6 (half0) / ==7 (half1), 16 lanes/wave.
// Store packing follows ckmap(sl&3,·)  (usec&3 == sl&3 since 8h ≡ 0 mod 4):
//   ty0: cols {0..5}         -> f4@0=(g0..g3), f2@4=(g4,g5)
//   ty1: cols {6,7,0,1,2,3}  -> f4@0=(g2..g5), f2@6=(g0,g1)
//   ty2: cols {4,5,6,7,0,1}  -> f2@0=(g4,g5), f4@4=(g0..g3)
//   ty3: cols {2..7}         -> f2@2=(g0,g1), f4@4=(g2..g5)
// All f4 at byte offsets ≡0 mod 16, f2 at ≡0 mod 8 (no splits, R13).
#define SEC_BWD(sl)                                                          \
    {                                                                        \
        const v2f KKs = KK * V##sl;           /* 1/n folded into K */        \
        const v2f P   = KKs * R##sl;          /* (g_b0, g_a0) */             \
        const v2f Q   = KKs * I##sl;                                         \
        const v2f G1  = fma2(c1v, P, s1v * Q); /* (g_b1, g_a1) */            \
        const v2f G2  = fma2(c2v, P, s2v * Q); /* (g_b2, g_a2) */            \
        float g0, g1, g2, g3, g4, g5;                                        \
        red6_g8(P.x, G1.x, G2.x, P.y, G1.y, G2.y,                            \
                g0, g1, g2, g3, g4, g5);                                     \
        if ((tid & 7) >= 6) {                                                \
            float* p = &gpart[tid >> 3][(sl) * 8 + 64 * half];               \
            if (((sl) & 3) == 0) {                                           \
                *(float4*)p       = make_float4(g0, g1, g2, g3);             \
                *(float2*)(p + 4) = make_float2(g4, g5);                     \
            } else if (((sl) & 3) == 1) {                                    \
                *(float4*)p       = make_float4(g2, g3, g4, g5);             \
                *(float2*)(p + 6) = make_float2(g0, g1);                     \
            } else if (((sl) & 3) == 2) {                                    \
                *(float2*)p       = make_float2(g4, g5);                     \
                *(float4*)(p + 4) = make_float4(g0, g1, g2, g3);             \
            } else {                                                         \
                *(float2*)(p + 2) = make_float2(g0, g1);                     \
                *(float4*)(p + 4) = make_float4(g2, g3, g4, g5);             \
            }                                                                \
        }                                                                    \
    }

    for (int it = 0; it < 1000; ++it) {
        // ---- forward: partial L over my 8 sections (logs grouped 4x) ----
        float L;
        v2f prod;
        prod.x = 1.0f; prod.y = 1.0f;
        SEC_PAIR(0, 1) SEC_PAIR(2, 3)
        L = __builtin_amdgcn_logf(prod.x) - __builtin_amdgcn_logf(prod.y);
        prod.x = 1.0f; prod.y = 1.0f;
        SEC_PAIR(4, 5) SEC_PAIR(6, 7)
        L += __builtin_amdgcn_logf(prod.x) - __builtin_amdgcn_logf(prod.y);

        // Pair exchange in-register: both lanes get the identical 16-section
        // total (add is commutative -> bit-identical K across the pair).
        const float Lt = pair_sum(L);

        const float mag   = __builtin_amdgcn_exp2f(0.5f * Lt);
        const float magpe = mag + 1e-8f;
        const float indB  = 6.020599913279624f * __builtin_amdgcn_logf(magpe);
        const float diff  = indB - tgt;
        const float K  = KC * diff * mag * rcp_nr(magpe);
        v2f KK; KK.x = K; KK.y = -K;     // A-side gradient sign folded here

        // ---- backward: scale directions, 2-stage DPP reduce, store ----
        SEC_BWD(0) SEC_BWD(1) SEC_BWD(2) SEC_BWD(3)
        SEC_BWD(4) SEC_BWD(5) SEC_BWD(6) SEC_BWD(7)
        __syncthreads();

        // ---- update: 8 threads/coeff; 8 x ds_read2_b32 fetch 16 row-
        //      partials (pairs r,r+1 via offset1 = GSTRIDE dwords) with
        //      hoisted addresses; tree-sum; 3-step DPP combine ----
        if (upd) {
            v2f p0, p1, p2, p3, p4, p5, p6, p7;
            asm volatile(
                "ds_read2_b32 %0, %8  offset0:0 offset1:132\n\t"
                "ds_read2_b32 %1, %9  offset0:0 offset1:132\n\t"
                "ds_read2_b32 %2, %10 offset0:0 offset1:132\n\t"
                "ds_read2_b32 %3, %11 offset0:0 offset1:132\n\t"
                "ds_read2_b32 %4, %12 offset0:0 offset1:132\n\t"
                "ds_read2_b32 %5, %13 offset0:0 offset1:132\n\t"
                "ds_read2_b32 %6, %14 offset0:0 offset1:132\n\t"
                "ds_read2_b32 %7, %15 offset0:0 offset1:132\n\t"
                "s_waitcnt lgkmcnt(0)"
                : "=&v"(p0), "=&v"(p1), "=&v"(p2), "=&v"(p3),
                  "=&v"(p4), "=&v"(p5), "=&v"(p6), "=&v"(p7)
                : "v"(ga0), "v"(ga1), "v"(ga2), "v"(ga3),
                  "v"(ga4), "v"(ga5), "v"(ga6), "v"(ga7)
                : "memory");
            const float s0 = p0.x + p0.y, s1_ = p1.x + p1.y;
            const float s2_ = p2.x + p2.y, s3 = p3.x + p3.y;
            const float s4 = p4.x + p4.y, s5 = p5.x + p5.y;
            const float s6 = p6.x + p6.y, s7 = p7.x + p7.y;
            float g = red1_g8(((s0 + s1_) + (s2_ + s3)) + ((s4 + s5) + (s6 + s7)));
            if (writer) {
                myc = fmaf(-0.1f, g, myc);
                sos[uscol] = myc;
            }
        }
        __syncthreads();
    }

    if (writer) out[u] = myc;
}

extern "C" void kernel_launch(void* const* d_in, const int* in_sizes, int n_in,
                              void* d_out, int out_size, void* d_ws, size_t ws_size,
                              hipStream_t stream) {
    const float* sos_in = (const float*)d_in[0];
    const float* target = (const float*)d_in[1];
    float* outp = (float*)d_out;
    hipLaunchKernelGGL(sgd_filter, dim3(1), dim3(TPB), 0, stream, sos_in, target, outp);
}

// Round 4
// 2778.927 us; speedup vs baseline: 1.0019x; 1.0019x over previous
//
#include <hip/hip_runtime.h>
#include <math.h>

#define TPB 1024   // 16 waves = 4/SIMD; thread = (freq = tid>>1, half = tid&1)
                   // PAIR LAYOUT: the two section-halves of a frequency are
                   // ADJACENT LANES -> L-exchange is one quad_perm DPP add,
                   // no Lpart LDS round-trip (2 barriers/iter).

typedef float v2f __attribute__((ext_vector_type(2)));

// Compiler-generated packed math only — NO hand-written v_pk_* asm (R5/R7).
static __device__ __forceinline__ v2f fma2(v2f a, v2f b, v2f c) {
    return __builtin_elementwise_fma(a, b, c);
}
static __device__ __forceinline__ float rcp_nr(float x) {
    float r = __builtin_amdgcn_rcpf(x);
    return r * fmaf(-x, r, 2.0f);
}
// RAW v_rcp_f32 (~1 ulp): NR step dropped (R16). Perturbation absorbed like
// the R4/R8/R12 reorders (absmax stayed 8-16x under threshold, contracting).
static __device__ __forceinline__ v2f rcp2(v2f x) {
    v2f r;
    r.x = __builtin_amdgcn_rcpf(x.x);
    r.y = __builtin_amdgcn_rcpf(x.y);
    return r;
}

// Both lanes of an even/odd pair get the pair total (commutative add ->
// bit-identical K on both lanes). s_nop 1 covers VALU->DPP hazard.
static __device__ __forceinline__ float pair_sum(float L) {
    asm("s_nop 1\n\t"
        "v_add_f32 %0, %0, %0 quad_perm:[1,0,3,2] row_mask:0xf bank_mask:0xf bound_ctrl:0"
        : "+v"(L));
    return L;
}

// Six independent HALF-AWARE 4-freq reductions: stage 1 = stride-2 add
// (combines the 2 same-half freqs of a quad), stage 2 = stride-4 add.
// Lanes (tid&7)==6 (half0) and ==7 (half1) hold the 4-freq group sums.
// Round-robin gives 6-inst spacing; s_nop 1 covers the entry hazard.
__device__ __forceinline__ void red6_g8(float i0, float i1, float i2,
                                        float i3, float i4, float i5,
                                        float& o0, float& o1, float& o2,
                                        float& o3, float& o4, float& o5) {
    asm("s_nop 1\n\t"
        "v_add_f32 %0, %6, %6  row_shr:2 row_mask:0xf bank_mask:0xf bound_ctrl:0\n\t"
        "v_add_f32 %3, %9, %9  row_shr:2 row_mask:0xf bank_mask:0xf bound_ctrl:0\n\t"
        "v_add_f32 %1, %7, %7  row_shr:2 row_mask:0xf bank_mask:0xf bound_ctrl:0\n\t"
        "v_add_f32 %4, %10, %10 row_shr:2 row_mask:0xf bank_mask:0xf bound_ctrl:0\n\t"
        "v_add_f32 %2, %8, %8  row_shr:2 row_mask:0xf bank_mask:0xf bound_ctrl:0\n\t"
        "v_add_f32 %5, %11, %11 row_shr:2 row_mask:0xf bank_mask:0xf bound_ctrl:0\n\t"
        "v_add_f32 %0, %0, %0 row_shr:4 row_mask:0xf bank_mask:0xf bound_ctrl:0\n\t"
        "v_add_f32 %3, %3, %3 row_shr:4 row_mask:0xf bank_mask:0xf bound_ctrl:0\n\t"
        "v_add_f32 %1, %1, %1 row_shr:4 row_mask:0xf bank_mask:0xf bound_ctrl:0\n\t"
        "v_add_f32 %4, %4, %4 row_shr:4 row_mask:0xf bank_mask:0xf bound_ctrl:0\n\t"
        "v_add_f32 %2, %2, %2 row_shr:4 row_mask:0xf bank_mask:0xf bound_ctrl:0\n\t"
        "v_add_f32 %5, %5, %5 row_shr:4 row_mask:0xf bank_mask:0xf bound_ctrl:0"
        : "=&v"(o0), "=&v"(o1), "=&v"(o2), "=&v"(o3), "=&v"(o4), "=&v"(o5)
        : "v"(i0), "v"(i1), "v"(i2), "v"(i3), "v"(i4), "v"(i5));
}

// Full-wave (64-lane) reduction of SIX independent values, rocPRIM-canonical
// ladder: shr:1,2,4,8 then row_bcast:15 (rows 1,3) + row_bcast:31 (rows 2,3).
// Lane 63 ends with the wave totals. Round-robin -> 6-inst hazard spacing.
__device__ __forceinline__ void wave_red6(float i0, float i1, float i2,
                                          float i3, float i4, float i5,
                                          float& o0, float& o1, float& o2,
                                          float& o3, float& o4, float& o5) {
    asm("s_nop 1\n\t"
        "v_add_f32 %0, %6, %6  row_shr:1 row_mask:0xf bank_mask:0xf bound_ctrl:0\n\t"
        "v_add_f32 %1, %7, %7  row_shr:1 row_mask:0xf bank_mask:0xf bound_ctrl:0\n\t"
        "v_add_f32 %2, %8, %8  row_shr:1 row_mask:0xf bank_mask:0xf bound_ctrl:0\n\t"
        "v_add_f32 %3, %9, %9  row_shr:1 row_mask:0xf bank_mask:0xf bound_ctrl:0\n\t"
        "v_add_f32 %4, %10, %10 row_shr:1 row_mask:0xf bank_mask:0xf bound_ctrl:0\n\t"
        "v_add_f32 %5, %11, %11 row_shr:1 row_mask:0xf bank_mask:0xf bound_ctrl:0\n\t"
        "v_add_f32 %0, %0, %0 row_shr:2 row_mask:0xf bank_mask:0xf bound_ctrl:0\n\t"
        "v_add_f32 %1, %1, %1 row_shr:2 row_mask:0xf bank_mask:0xf bound_ctrl:0\n\t"
        "v_add_f32 %2, %2, %2 row_shr:2 row_mask:0xf bank_mask:0xf bound_ctrl:0\n\t"
        "v_add_f32 %3, %3, %3 row_shr:2 row_mask:0xf bank_mask:0xf bound_ctrl:0\n\t"
        "v_add_f32 %4, %4, %4 row_shr:2 row_mask:0xf bank_mask:0xf bound_ctrl:0\n\t"
        "v_add_f32 %5, %5, %5 row_shr:2 row_mask:0xf bank_mask:0xf bound_ctrl:0\n\t"
        "v_add_f32 %0, %0, %0 row_shr:4 row_mask:0xf bank_mask:0xf bound_ctrl:0\n\t"
        "v_add_f32 %1, %1, %1 row_shr:4 row_mask:0xf bank_mask:0xf bound_ctrl:0\n\t"
        "v_add_f32 %2, %2, %2 row_shr:4 row_mask:0xf bank_mask:0xf bound_ctrl:0\n\t"
        "v_add_f32 %3, %3, %3 row_shr:4 row_mask:0xf bank_mask:0xf bound_ctrl:0\n\t"
        "v_add_f32 %4, %4, %4 row_shr:4 row_mask:0xf bank_mask:0xf bound_ctrl:0\n\t"
        "v_add_f32 %5, %5, %5 row_shr:4 row_mask:0xf bank_mask:0xf bound_ctrl:0\n\t"
        "v_add_f32 %0, %0, %0 row_shr:8 row_mask:0xf bank_mask:0xf bound_ctrl:0\n\t"
        "v_add_f32 %1, %1, %1 row_shr:8 row_mask:0xf bank_mask:0xf bound_ctrl:0\n\t"
        "v_add_f32 %2, %2, %2 row_shr:8 row_mask:0xf bank_mask:0xf bound_ctrl:0\n\t"
        "v_add_f32 %3, %3, %3 row_shr:8 row_mask:0xf bank_mask:0xf bound_ctrl:0\n\t"
        "v_add_f32 %4, %4, %4 row_shr:8 row_mask:0xf bank_mask:0xf bound_ctrl:0\n\t"
        "v_add_f32 %5, %5, %5 row_shr:8 row_mask:0xf bank_mask:0xf bound_ctrl:0\n\t"
        "v_add_f32 %0, %0, %0 row_bcast:15 row_mask:0xa bank_mask:0xf\n\t"
        "v_add_f32 %1, %1, %1 row_bcast:15 row_mask:0xa bank_mask:0xf\n\t"
        "v_add_f32 %2, %2, %2 row_bcast:15 row_mask:0xa bank_mask:0xf\n\t"
        "v_add_f32 %3, %3, %3 row_bcast:15 row_mask:0xa bank_mask:0xf\n\t"
        "v_add_f32 %4, %4, %4 row_bcast:15 row_mask:0xa bank_mask:0xf\n\t"
        "v_add_f32 %5, %5, %5 row_bcast:15 row_mask:0xa bank_mask:0xf\n\t"
        "v_add_f32 %0, %0, %0 row_bcast:31 row_mask:0xc bank_mask:0xf\n\t"
        "v_add_f32 %1, %1, %1 row_bcast:31 row_mask:0xc bank_mask:0xf\n\t"
        "v_add_f32 %2, %2, %2 row_bcast:31 row_mask:0xc bank_mask:0xf\n\t"
        "v_add_f32 %3, %3, %3 row_bcast:31 row_mask:0xc bank_mask:0xf\n\t"
        "v_add_f32 %4, %4, %4 row_bcast:31 row_mask:0xc bank_mask:0xf\n\t"
        "v_add_f32 %5, %5, %5 row_bcast:31 row_mask:0xc bank_mask:0xf"
        : "=&v"(o0), "=&v"(o1), "=&v"(o2), "=&v"(o3), "=&v"(o4), "=&v"(o5)
        : "v"(i0), "v"(i1), "v"(i2), "v"(i3), "v"(i4), "v"(i5));
}

// coefficient k (0..5 = b0,b1,b2,a0,a1,a2) -> paired column in
// [b0 a0 b1 a1 b2 a2]: b0,b1,b2 -> 0,2,4 ; a0,a1,a2 -> 1,3,5
__device__ __forceinline__ int cmap(int k) {
    return (k < 3) ? 2 * k : 2 * k - 5;
}

// GSTRIDE=164 (R4 bank derivation, per 32-LANE PHASE — the R3 lesson):
//  - backward f4 writes: active lanes per phase = rows r..r+3 x half {0,1};
//    quad-start = (r*41 + 20*half + 2*sl) mod 8 = (r + 4*half + 2*sl) mod 8
//    -> 8 distinct quads -> CONFLICT-FREE (the old 64*half offset was ==0
//    mod 32 and collided halves; 80*half == 4*half mod 32 fixes it).
//  - update b128 reads: 8 consecutive lanes, quad = (lane + cb/4) mod 8
//    -> distinct -> CONFLICT-FREE.  164*4 == 0 mod 16 (no f4 splits, R13).
#define GSTRIDE 164

__global__
__attribute__((amdgpu_flat_work_group_size(TPB, TPB), amdgpu_waves_per_eu(4, 4)))
void sgd_filter(const float* __restrict__ sos_in,
                const float* __restrict__ target,
                float* __restrict__ out) {
    // 16 sections x 6 floats, PAIRED, NO pad: [b0 a0 b1 a1 b2 a2].
    __shared__ __align__(16) float sos[96];
    // 128 rows (row = tid>>3 = one 4-freq group); section s at col base
    // 8*(s&7) + 80*(s>>3), cols +0..5 = (g_b0,g_b1,g_b2,g_a0,g_a1,g_a2).
    __shared__ __align__(16) float gpart[128][GSTRIDE];

    const int tid  = threadIdx.x;
    const int fr   = tid >> 1;     // frequency (lane pairs share it)
    const int half = tid & 1;      // section half: 0 -> s0..7, 1 -> s8..15
    const float* secbase = &sos[half * 48];   // 8 sections x 6 floats

    if (tid < 96) sos[(tid / 6) * 6 + cmap(tid % 6)] = sos_in[tid];

    // Update identity (R4): wave wv owns section wv; lane ln reads rows
    // ln and ln+64 of the section's 6 columns; lane 63 owns the 6 coeffs.
    const int wv = tid >> 6;
    const int ln = tid & 63;
    const int cb = (wv & 7) * 8 + 80 * (wv >> 3);
    const float* rp0 = &gpart[ln][cb];
    const float* rp1 = &gpart[ln + 64][cb];
    const bool owner = (ln == 63);
    // Running coefficients live in lane-63 registers (sos is the shared copy).
    float kb0 = 0.f, kb1 = 0.f, kb2 = 0.f, ka0 = 0.f, ka1 = 0.f, ka2 = 0.f;
    if (owner) {
        kb0 = sos_in[6 * wv + 0]; kb1 = sos_in[6 * wv + 1];
        kb2 = sos_in[6 * wv + 2]; ka0 = sos_in[6 * wv + 3];
        ka1 = sos_in[6 * wv + 4]; ka2 = sos_in[6 * wv + 5];
    }

    // Per-frequency constants
    const float w  = (float)((double)fr * (3.14159265358979323846 / 511.0));
    const float c1 = cosf(w);
    const float s1 = -sinf(w);           // z1 = e^{-jw}
    const float c2 = c1 * c1 - s1 * s1;  // z2 = z1^2
    const float s2 = 2.0f * c1 * s1;
    const float tgt = target[fr];
    const float KC = 40.0f / (512.0f * 2.302585092994046f); // 40/(n*ln10)

    v2f c1v; c1v.x = c1; c1v.y = c1;
    v2f s1v; s1v.x = s1; s1v.y = s1;
    v2f c2v; c2v.x = c2; c2v.y = c2;
    v2f s2v; s2v.x = s2; s2v.y = s2;

    __syncthreads();

    // 8 sections/thread: Re, Im, 1/n kept (1/n folded into K in backward).
    v2f R0, R1, R2, R3, R4, R5, R6, R7;
    v2f I0, I1, I2, I3, I4, I5, I6, I7;
    v2f V0, V1, V2, V3, V4, V5, V6, V7;

// Two sections per 3 x ds_read_b128 (12 LDS reads/thread vs 16 padded);
// half addresses 48 floats apart (banks +16) -> disjoint, broadcast within
// each half: conflict-free.
#define SEC_PAIR(sa, sb)                                                     \
    {                                                                        \
        const float4 q0 = *(const float4*)(secbase + (sa) * 6);              \
        const float4 q1 = *(const float4*)(secbase + (sa) * 6 + 4);          \
        const float4 q2 = *(const float4*)(secbase + (sa) * 6 + 8);          \
        v2f ba0, ba1, ba2;                                                   \
        ba0.x = q0.x; ba0.y = q0.y;                                          \
        ba1.x = q0.z; ba1.y = q0.w;                                          \
        ba2.x = q1.x; ba2.y = q1.y;                                          \
        R##sa = fma2(ba2, c2v, fma2(ba1, c1v, ba0));                         \
        I##sa = fma2(ba2, s2v, ba1 * s1v);                                   \
        {                                                                    \
            const v2f n = fma2(R##sa, R##sa, I##sa * I##sa);                 \
            prod = prod * n;                                                 \
            V##sa = rcp2(n);                                                 \
        }                                                                    \
        ba0.x = q1.z; ba0.y = q1.w;                                          \
        ba1.x = q2.x; ba1.y = q2.y;                                          \
        ba2.x = q2.z; ba2.y = q2.w;                                          \
        R##sb = fma2(ba2, c2v, fma2(ba1, c1v, ba0));                         \
        I##sb = fma2(ba2, s2v, ba1 * s1v);                                   \
        {                                                                    \
            const v2f n = fma2(R##sb, R##sb, I##sb * I##sb);                 \
            prod = prod * n;                                                 \
            V##sb = rcp2(n);                                                 \
        }                                                                    \
    }

// Backward: scale stored directions, 2-stage DPP reduce (4 freqs/group),
// writers = lanes (tid&7)==6 (half0) / ==7 (half1), 16 lanes/wave.
// Uniform packing: f4 = (g_b0,g_b1,g_b2,g_a0) @ col 8*sl+80*half, f2 =
// (g_a1,g_a2) @ +4.  Conflict-free per phase (see GSTRIDE derivation).
#define SEC_BWD(sl)                                                          \
    {                                                                        \
        const v2f KKs = KK * V##sl;           /* 1/n folded into K */        \
        const v2f P   = KKs * R##sl;          /* (g_b0, g_a0) */             \
        const v2f Q   = KKs * I##sl;                                         \
        const v2f G1  = fma2(c1v, P, s1v * Q); /* (g_b1, g_a1) */            \
        const v2f G2  = fma2(c2v, P, s2v * Q); /* (g_b2, g_a2) */            \
        float g0, g1, g2, g3, g4, g5;                                        \
        red6_g8(P.x, G1.x, G2.x, P.y, G1.y, G2.y,                            \
                g0, g1, g2, g3, g4, g5);                                     \
        if ((tid & 7) >= 6) {                                                \
            float* p = &gpart[tid >> 3][8 * (sl) + 80 * half];               \
            *(float4*)p       = make_float4(g0, g1, g2, g3);                 \
            *(float2*)(p + 4) = make_float2(g4, g5);                         \
        }                                                                    \
    }

    for (int it = 0; it < 1000; ++it) {
        // ---- forward: partial L over my 8 sections (logs grouped 4x) ----
        float L;
        v2f prod;
        prod.x = 1.0f; prod.y = 1.0f;
        SEC_PAIR(0, 1) SEC_PAIR(2, 3)
        L = __builtin_amdgcn_logf(prod.x) - __builtin_amdgcn_logf(prod.y);
        prod.x = 1.0f; prod.y = 1.0f;
        SEC_PAIR(4, 5) SEC_PAIR(6, 7)
        L += __builtin_amdgcn_logf(prod.x) - __builtin_amdgcn_logf(prod.y);

        // Pair exchange in-register: both lanes get the identical 16-section
        // total (add is commutative -> bit-identical K across the pair).
        const float Lt = pair_sum(L);

        const float mag   = __builtin_amdgcn_exp2f(0.5f * Lt);
        const float magpe = mag + 1e-8f;
        const float indB  = 6.020599913279624f * __builtin_amdgcn_logf(magpe);
        const float diff  = indB - tgt;
        const float K  = KC * diff * mag * rcp_nr(magpe);
        v2f KK; KK.x = K; KK.y = -K;     // A-side gradient sign folded here

        // ---- backward: scale directions, 2-stage DPP reduce, store ----
        SEC_BWD(0) SEC_BWD(1) SEC_BWD(2) SEC_BWD(3)
        SEC_BWD(4) SEC_BWD(5) SEC_BWD(6) SEC_BWD(7)
        __syncthreads();

        // ---- update (R4): wave wv = section wv; 2x(b128+b64) conflict-free
        //      reads, 6 scalar adds, 6-value full-wave DPP reduce; lane 63
        //      applies SGD and writes sos (f4+f2). All 16 waves active. ----
        {
            const float4 qa = *(const float4*)rp0;
            const float2 qb = *(const float2*)(rp0 + 4);
            const float4 qc = *(const float4*)rp1;
            const float2 qd = *(const float2*)(rp1 + 4);
            const float s0 = qa.x + qc.x, s1_ = qa.y + qc.y;
            const float s2_ = qa.z + qc.z, s3 = qa.w + qc.w;
            const float s4 = qb.x + qd.x, s5 = qb.y + qd.y;
            float t0, t1, t2, t3, t4, t5;
            wave_red6(s0, s1_, s2_, s3, s4, s5, t0, t1, t2, t3, t4, t5);
            if (owner) {
                kb0 = fmaf(-0.1f, t0, kb0);
                kb1 = fmaf(-0.1f, t1, kb1);
                kb2 = fmaf(-0.1f, t2, kb2);
                ka0 = fmaf(-0.1f, t3, ka0);
                ka1 = fmaf(-0.1f, t4, ka1);
                ka2 = fmaf(-0.1f, t5, ka2);
                float* sp = &sos[6 * wv];
                *(float4*)sp       = make_float4(kb0, ka0, kb1, ka1);
                *(float2*)(sp + 4) = make_float2(kb2, ka2);
            }
        }
        __syncthreads();
    }

    if (owner) {
        float2* o = (float2*)&out[6 * wv];
        o[0] = make_float2(kb0, kb1);
        o[1] = make_float2(kb2, ka0);
        o[2] = make_float2(ka1, ka2);
    }
}

extern "C" void kernel_launch(void* const* d_in, const int* in_sizes, int n_in,
                              void* d_out, int out_size, void* d_ws, size_t ws_size,
                              hipStream_t stream) {
    const float* sos_in = (const float*)d_in[0];
    const float* target = (const float*)d_in[1];
    float* outp = (float*)d_out;
    hipLaunchKernelGGL(sgd_filter, dim3(1), dim3(TPB), 0, stream, sos_in, target, outp);
}

// Round 5
// 2212.821 us; speedup vs baseline: 1.2582x; 1.2558x over previous
//
#include <hip/hip_runtime.h>
#include <math.h>

#define TPB 1024   // 16 waves = 4/SIMD. QUAD LAYOUT (R5): thread =
                   // (qd = tid>>2 -> freqs 2qd,2qd+1 ; pos = tid&3 ->
                   // sections 4*pos..4*pos+3). Halves forward LDS reads
                   // (6 b128/thread) and backward stores; L-reduce is a
                   // 4-lane quad butterfly. 2 barriers/iter.

typedef float v2f __attribute__((ext_vector_type(2)));

static __device__ __forceinline__ v2f mk2(float x, float y) {
    v2f r; r.x = x; r.y = y; return r;
}
// Compiler-generated packed math only — NO hand-written v_pk_* asm (R5/R7).
static __device__ __forceinline__ v2f fma2(v2f a, v2f b, v2f c) {
    return __builtin_elementwise_fma(a, b, c);
}
static __device__ __forceinline__ float rcp_nr(float x) {
    float r = __builtin_amdgcn_rcpf(x);
    return r * fmaf(-x, r, 2.0f);
}
// RAW v_rcp_f32 (~1 ulp): NR step dropped (R16 of prior session).
static __device__ __forceinline__ v2f rcp2(v2f x) {
    v2f r;
    r.x = __builtin_amdgcn_rcpf(x.x);
    r.y = __builtin_amdgcn_rcpf(x.y);
    return r;
}

// Quad all-reduce of TWO independent values: xor1 (quad_perm [1,0,3,2])
// then xor2 ([2,3,0,1]). ALL 4 lanes end with the bit-identical total
// (pairwise tree + commutative adds). s_nops cover DPP read-after-VALU.
static __device__ __forceinline__ void quad_allsum2(float& a, float& b) {
    asm("s_nop 1\n\t"
        "v_add_f32 %0, %0, %0 quad_perm:[1,0,3,2] row_mask:0xf bank_mask:0xf bound_ctrl:0\n\t"
        "v_add_f32 %1, %1, %1 quad_perm:[1,0,3,2] row_mask:0xf bank_mask:0xf bound_ctrl:0\n\t"
        "s_nop 0\n\t"
        "v_add_f32 %0, %0, %0 quad_perm:[2,3,0,1] row_mask:0xf bank_mask:0xf bound_ctrl:0\n\t"
        "v_add_f32 %1, %1, %1 quad_perm:[2,3,0,1] row_mask:0xf bank_mask:0xf bound_ctrl:0"
        : "+v"(a), "+v"(b));
}

// Six independent same-pos reductions across the 4 quads of a 16-lane row:
// stride-4 then stride-8 shifts; lanes 12..15 (pos 0..3) hold the 4-quad
// (=8-freq) sums of their own section set. Round-robin -> 6-inst spacing.
__device__ __forceinline__ void red6_s48(float i0, float i1, float i2,
                                         float i3, float i4, float i5,
                                         float& o0, float& o1, float& o2,
                                         float& o3, float& o4, float& o5) {
    asm("s_nop 1\n\t"
        "v_add_f32 %0, %6, %6  row_shr:4 row_mask:0xf bank_mask:0xf bound_ctrl:0\n\t"
        "v_add_f32 %3, %9, %9  row_shr:4 row_mask:0xf bank_mask:0xf bound_ctrl:0\n\t"
        "v_add_f32 %1, %7, %7  row_shr:4 row_mask:0xf bank_mask:0xf bound_ctrl:0\n\t"
        "v_add_f32 %4, %10, %10 row_shr:4 row_mask:0xf bank_mask:0xf bound_ctrl:0\n\t"
        "v_add_f32 %2, %8, %8  row_shr:4 row_mask:0xf bank_mask:0xf bound_ctrl:0\n\t"
        "v_add_f32 %5, %11, %11 row_shr:4 row_mask:0xf bank_mask:0xf bound_ctrl:0\n\t"
        "v_add_f32 %0, %0, %0 row_shr:8 row_mask:0xf bank_mask:0xf bound_ctrl:0\n\t"
        "v_add_f32 %3, %3, %3 row_shr:8 row_mask:0xf bank_mask:0xf bound_ctrl:0\n\t"
        "v_add_f32 %1, %1, %1 row_shr:8 row_mask:0xf bank_mask:0xf bound_ctrl:0\n\t"
        "v_add_f32 %4, %4, %4 row_shr:8 row_mask:0xf bank_mask:0xf bound_ctrl:0\n\t"
        "v_add_f32 %2, %2, %2 row_shr:8 row_mask:0xf bank_mask:0xf bound_ctrl:0\n\t"
        "v_add_f32 %5, %5, %5 row_shr:8 row_mask:0xf bank_mask:0xf bound_ctrl:0"
        : "=&v"(o0), "=&v"(o1), "=&v"(o2), "=&v"(o3), "=&v"(o4), "=&v"(o5)
        : "v"(i0), "v"(i1), "v"(i2), "v"(i3), "v"(i4), "v"(i5));
}

// 8-lane combine for the update stage: lane (tid&7)==7 gets the group sum.
__device__ __forceinline__ float red1_g8(float g) {
    asm("s_nop 1\n\t"
        "v_add_f32 %0, %0, %0 row_shr:1 row_mask:0xf bank_mask:0xf bound_ctrl:0\n\t"
        "s_nop 1\n\t"
        "v_add_f32 %0, %0, %0 row_shr:2 row_mask:0xf bank_mask:0xf bound_ctrl:0\n\t"
        "s_nop 1\n\t"
        "v_add_f32 %0, %0, %0 row_shr:4 row_mask:0xf bank_mask:0xf bound_ctrl:0"
        : "+v"(g));
    return g;
}

// coefficient k (0..5 = b0,b1,b2,a0,a1,a2) -> paired column in
// [b0 a0 b1 a1 b2 a2]: b0,b1,b2 -> 0,2,4 ; a0,a1,a2 -> 1,3,5
__device__ __forceinline__ int cmap(int k) {
    return (k < 3) ? 2 * k : 2 * k - 5;
}

// GPAD=100 (per 32-LANE-PHASE bank derivation, R3/R4 method):
//  - backward f4 stores: 8 writer lanes/phase (rows r,r+1 x pos 0..3);
//    quad-start = (4r + 24p + 6sl)/4 mod 8 -> {0,2,4,6}+c U {1,3,5,7}+c
//    distinct -> CONFLICT-FREE.  f2 stores: disjoint bank pairs -> free.
//  - update b32 reads: bank = (25*(oct+8j) + u) mod 32 -> worst 2-way (free).
//  - 100*4 = 400 == 0 mod 16: no f4 splits (R13).
#define GPAD 100

__global__
__attribute__((amdgpu_flat_work_group_size(TPB, TPB), amdgpu_waves_per_eu(4, 4)))
void sgd_filter(const float* __restrict__ sos_in,
                const float* __restrict__ target,
                float* __restrict__ out) {
    // 16 sections x 6 floats, PAIRED: [b0 a0 b1 a1 b2 a2] per section.
    __shared__ __align__(16) float sos[96];
    // 64 rows (row = tid>>4, one 16-lane group = 8 freqs); col = coeff id
    // 0..95 = sec*6 + [b0,b1,b2,a0,a1,a2].
    __shared__ __align__(16) float gpart[64][GPAD];

    const int tid = threadIdx.x;
    const int qd  = tid >> 2;      // freq group: freqs 2qd, 2qd+1
    const int pos = tid & 3;       // section group: 4*pos .. 4*pos+3
    const float* secbase = &sos[pos * 24];

    if (tid < 96) sos[(tid / 6) * 6 + cmap(tid % 6)] = sos_in[tid];

    // Update identity: 8 threads per coefficient u = tid>>3 (tid<768).
    const int u    = tid >> 3;
    const int oct  = tid & 7;
    const int usec = u / 6, uk = u % 6;
    const int uscol = usec * 6 + cmap(uk);    // sos col (paired layout)
    const bool upd = (tid < 768);
    const bool writer = upd && (oct == 7);
    float myc = 0.0f;
    if (writer) myc = sos_in[u];
    const float* urp = &gpart[oct][0] + u;    // rows oct+8j, col u

    // Per-thread frequency constants (two freqs)
    const double step = 3.14159265358979323846 / 511.0;
    const float w0 = (float)((double)(2 * qd) * step);
    const float w1 = (float)((double)(2 * qd + 1) * step);
    const float c10 = cosf(w0), s10 = -sinf(w0);
    const float c20 = c10 * c10 - s10 * s10, s20 = 2.0f * c10 * s10;
    const float c11 = cosf(w1), s11 = -sinf(w1);
    const float c21 = c11 * c11 - s11 * s11, s21 = 2.0f * c11 * s11;
    const float2 tg = *(const float2*)&target[2 * qd];
    const float KC = 40.0f / (512.0f * 2.302585092994046f); // 40/(n*ln10)

    const v2f c1v0 = mk2(c10, c10), s1v0 = mk2(s10, s10);
    const v2f c2v0 = mk2(c20, c20), s2v0 = mk2(s20, s20);
    const v2f c1v1 = mk2(c11, c11), s1v1 = mk2(s11, s11);
    const v2f c2v1 = mk2(c21, c21), s2v1 = mk2(s21, s21);

    __syncthreads();

    // 4 sections x 2 freqs: Re, Im, 1/n per eval (A = freq0, B = freq1).
    v2f RA0, RA1, RA2, RA3, IA0, IA1, IA2, IA3, VA0, VA1, VA2, VA3;
    v2f RB0, RB1, RB2, RB3, IB0, IB1, IB2, IB3, VB0, VB1, VB2, VB3;

// One section, BOTH freqs (coefficient pair regs shared).
#define SEC_EVAL(sl, BA0, BA1, BA2)                                          \
    {                                                                        \
        const v2f ba0 = BA0, ba1 = BA1, ba2 = BA2;                           \
        RA##sl = fma2(ba2, c2v0, fma2(ba1, c1v0, ba0));                      \
        IA##sl = fma2(ba2, s2v0, ba1 * s1v0);                                \
        {                                                                    \
            const v2f n = fma2(RA##sl, RA##sl, IA##sl * IA##sl);             \
            prod0 = prod0 * n;                                               \
            VA##sl = rcp2(n);                                                \
        }                                                                    \
        RB##sl = fma2(ba2, c2v1, fma2(ba1, c1v1, ba0));                      \
        IB##sl = fma2(ba2, s2v1, ba1 * s1v1);                                \
        {                                                                    \
            const v2f n = fma2(RB##sl, RB##sl, IB##sl * IB##sl);             \
            prod1 = prod1 * n;                                               \
            VB##sl = rcp2(n);                                                \
        }                                                                    \
    }

// Backward: per section, per-freq (P,Q,G1,G2) then freq-pair pk-add, then
// stride-4/8 DPP reduce across the 4 quads of the 16-lane row. Writers =
// lanes (tid&15)>=12; row = tid>>4; cols 24*pos + 6*sl (+0..5 =
// b0,b1,b2,a0,a1,a2). Conflict-free (see GPAD derivation).
#define SEC_BWD(sl)                                                          \
    {                                                                        \
        const v2f KA = KK0 * VA##sl;                                         \
        const v2f PA = KA * RA##sl;                                          \
        const v2f QA = KA * IA##sl;                                          \
        const v2f KB = KK1 * VB##sl;                                         \
        const v2f PB = KB * RB##sl;                                          \
        const v2f QB = KB * IB##sl;                                          \
        const v2f P  = PA + PB;                                              \
        const v2f G1 = fma2(c1v0, PA, s1v0 * QA) + fma2(c1v1, PB, s1v1 * QB);\
        const v2f G2 = fma2(c2v0, PA, s2v0 * QA) + fma2(c2v1, PB, s2v1 * QB);\
        float g0, g1, g2, g3, g4, g5;                                        \
        red6_s48(P.x, G1.x, G2.x, P.y, G1.y, G2.y,                           \
                 g0, g1, g2, g3, g4, g5);                                    \
        if ((tid & 15) >= 12) {                                              \
            float* p = &gpart[tid >> 4][24 * pos + 6 * (sl)];                \
            *(float4*)p       = make_float4(g0, g1, g2, g3);                 \
            *(float2*)(p + 4) = make_float2(g4, g5);                         \
        }                                                                    \
    }

    for (int it = 0; it < 1000; ++it) {
        // ---- forward: 6 b128 loads cover my 4 sections (conflict-free
        //      broadcast); evaluate both freqs; logs grouped 4x as before.
        const float4 q0 = *(const float4*)(secbase + 0);
        const float4 q1 = *(const float4*)(secbase + 4);
        const float4 q2 = *(const float4*)(secbase + 8);
        const float4 q3 = *(const float4*)(secbase + 12);
        const float4 q4 = *(const float4*)(secbase + 16);
        const float4 q5 = *(const float4*)(secbase + 20);
        v2f prod0 = mk2(1.0f, 1.0f), prod1 = mk2(1.0f, 1.0f);
        SEC_EVAL(0, mk2(q0.x, q0.y), mk2(q0.z, q0.w), mk2(q1.x, q1.y))
        SEC_EVAL(1, mk2(q1.z, q1.w), mk2(q2.x, q2.y), mk2(q2.z, q2.w))
        SEC_EVAL(2, mk2(q3.x, q3.y), mk2(q3.z, q3.w), mk2(q4.x, q4.y))
        SEC_EVAL(3, mk2(q4.z, q4.w), mk2(q5.x, q5.y), mk2(q5.z, q5.w))
        float L0 = __builtin_amdgcn_logf(prod0.x) - __builtin_amdgcn_logf(prod0.y);
        float L1 = __builtin_amdgcn_logf(prod1.x) - __builtin_amdgcn_logf(prod1.y);

        // Quad butterfly: every lane gets the bit-identical 16-section total
        // for both of its freqs.
        quad_allsum2(L0, L1);

        const float mag0   = __builtin_amdgcn_exp2f(0.5f * L0);
        const float magpe0 = mag0 + 1e-8f;
        const float indB0  = 6.020599913279624f * __builtin_amdgcn_logf(magpe0);
        const float K0 = KC * (indB0 - tg.x) * mag0 * rcp_nr(magpe0);
        const float mag1   = __builtin_amdgcn_exp2f(0.5f * L1);
        const float magpe1 = mag1 + 1e-8f;
        const float indB1  = 6.020599913279624f * __builtin_amdgcn_logf(magpe1);
        const float K1 = KC * (indB1 - tg.y) * mag1 * rcp_nr(magpe1);
        const v2f KK0 = mk2(K0, -K0);   // A-side gradient sign folded here
        const v2f KK1 = mk2(K1, -K1);

        // ---- backward: 4 sections, freq-pair add + stride-4/8 DPP, store --
        SEC_BWD(0) SEC_BWD(1) SEC_BWD(2) SEC_BWD(3)
        __syncthreads();

        // ---- update: 8 threads/coeff, 8 rows each (stride 8 = 800 floats),
        //      <=2-way banks, tree-sum, then 3-step DPP combine ----
        if (upd) {
            const float r0 = urp[0],        r1 = urp[1 * 8 * GPAD];
            const float r2 = urp[2 * 8 * GPAD], r3 = urp[3 * 8 * GPAD];
            const float r4 = urp[4 * 8 * GPAD], r5 = urp[5 * 8 * GPAD];
            const float r6 = urp[6 * 8 * GPAD], r7 = urp[7 * 8 * GPAD];
            float g = red1_g8(((r0 + r1) + (r2 + r3)) + ((r4 + r5) + (r6 + r7)));
            if (writer) {
                myc = fmaf(-0.1f, g, myc);
                sos[uscol] = myc;
            }
        }
        __syncthreads();
    }

    if (writer) out[u] = myc;
}

extern "C" void kernel_launch(void* const* d_in, const int* in_sizes, int n_in,
                              void* d_out, int out_size, void* d_ws, size_t ws_size,
                              hipStream_t stream) {
    const float* sos_in = (const float*)d_in[0];
    const float* target = (const float*)d_in[1];
    float* outp = (float*)d_out;
    hipLaunchKernelGGL(sgd_filter, dim3(1), dim3(TPB), 0, stream, sos_in, target, outp);
}

// Round 6
// 2014.488 us; speedup vs baseline: 1.3820x; 1.0985x over previous
//
#include <hip/hip_runtime.h>
#include <math.h>

#define TPB 1024   // 16 waves = 4/SIMD. QUAD LAYOUT (R5): thread =
                   // (qd = tid>>2 -> freqs 2qd,2qd+1 ; pos = tid&3 ->
                   // sections 4*pos..4*pos+3). 2 barriers/iter.
                   // R6: batched-rcp (16->4 v_rcp), 1-stage backward DPP,
                   // raw-rcp K chain. VALU-issue-bound -> fewer insts.

typedef float v2f __attribute__((ext_vector_type(2)));

static __device__ __forceinline__ v2f mk2(float x, float y) {
    v2f r; r.x = x; r.y = y; return r;
}
// Compiler-generated packed math only — NO hand-written v_pk_* asm (R5/R7).
static __device__ __forceinline__ v2f fma2(v2f a, v2f b, v2f c) {
    return __builtin_elementwise_fma(a, b, c);
}
// RAW v_rcp_f32 (~1 ulp): NR dropped (R16). R6 batches 4 section inverses
// through ONE product reciprocal (prefix/suffix recovery): TRANS 16->4
// v_rcp per thread. Error class ~4 ulp — same family as prior reorders
// (absmax stayed 8-16x under threshold; trajectory contracting).
static __device__ __forceinline__ v2f rcp2(v2f x) {
    v2f r;
    r.x = __builtin_amdgcn_rcpf(x.x);
    r.y = __builtin_amdgcn_rcpf(x.y);
    return r;
}

// Quad all-reduce of TWO independent values: xor1 (quad_perm [1,0,3,2])
// then xor2 ([2,3,0,1]). ALL 4 lanes end with the bit-identical total
// (pairwise tree + commutative adds). s_nops cover DPP read-after-VALU.
static __device__ __forceinline__ void quad_allsum2(float& a, float& b) {
    asm("s_nop 1\n\t"
        "v_add_f32 %0, %0, %0 quad_perm:[1,0,3,2] row_mask:0xf bank_mask:0xf bound_ctrl:0\n\t"
        "v_add_f32 %1, %1, %1 quad_perm:[1,0,3,2] row_mask:0xf bank_mask:0xf bound_ctrl:0\n\t"
        "s_nop 0\n\t"
        "v_add_f32 %0, %0, %0 quad_perm:[2,3,0,1] row_mask:0xf bank_mask:0xf bound_ctrl:0\n\t"
        "v_add_f32 %1, %1, %1 quad_perm:[2,3,0,1] row_mask:0xf bank_mask:0xf bound_ctrl:0"
        : "+v"(a), "+v"(b));
}

// SINGLE-stage cross-quad combine (R6: shr:8 only — half the DPP of R5).
// Lane l>=8 of each 16-row gets v(l)+v(l-8): lanes 8..11 = quads{0,2},
// lanes 12..15 = quads{1,3}, each a 2-freq-pair (4-freq) partial.
__device__ __forceinline__ void red6_s8(float i0, float i1, float i2,
                                        float i3, float i4, float i5,
                                        float& o0, float& o1, float& o2,
                                        float& o3, float& o4, float& o5) {
    asm("s_nop 1\n\t"
        "v_add_f32 %0, %6, %6  row_shr:8 row_mask:0xf bank_mask:0xf bound_ctrl:0\n\t"
        "v_add_f32 %3, %9, %9  row_shr:8 row_mask:0xf bank_mask:0xf bound_ctrl:0\n\t"
        "v_add_f32 %1, %7, %7  row_shr:8 row_mask:0xf bank_mask:0xf bound_ctrl:0\n\t"
        "v_add_f32 %4, %10, %10 row_shr:8 row_mask:0xf bank_mask:0xf bound_ctrl:0\n\t"
        "v_add_f32 %2, %8, %8  row_shr:8 row_mask:0xf bank_mask:0xf bound_ctrl:0\n\t"
        "v_add_f32 %5, %11, %11 row_shr:8 row_mask:0xf bank_mask:0xf bound_ctrl:0"
        : "=&v"(o0), "=&v"(o1), "=&v"(o2), "=&v"(o3), "=&v"(o4), "=&v"(o5)
        : "v"(i0), "v"(i1), "v"(i2), "v"(i3), "v"(i4), "v"(i5));
}

// 8-lane combine for the update stage: lane (tid&7)==7 gets the group sum.
__device__ __forceinline__ float red1_g8(float g) {
    asm("s_nop 1\n\t"
        "v_add_f32 %0, %0, %0 row_shr:1 row_mask:0xf bank_mask:0xf bound_ctrl:0\n\t"
        "s_nop 1\n\t"
        "v_add_f32 %0, %0, %0 row_shr:2 row_mask:0xf bank_mask:0xf bound_ctrl:0\n\t"
        "s_nop 1\n\t"
        "v_add_f32 %0, %0, %0 row_shr:4 row_mask:0xf bank_mask:0xf bound_ctrl:0"
        : "+v"(g));
    return g;
}

// coefficient k (0..5 = b0,b1,b2,a0,a1,a2) -> paired column in
// [b0 a0 b1 a1 b2 a2]: b0,b1,b2 -> 0,2,4 ; a0,a1,a2 -> 1,3,5
__device__ __forceinline__ int cmap(int k) {
    return (k < 3) ? 2 * k : 2 * k - 5;
}

// GPAD=100 (per 32-LANE-PHASE bank derivation — the R3/R4 method):
//  - backward f4 stores (16 writers/phase, rows R=2r..2r+3, pos 0..3):
//    quad = (25R + 6p + 6sl) mod 8 = (R + 6p) mod 8 + c -> each quad hit
//    exactly 2x -> 2-way (FREE, m136). f2 stores likewise 2-way.
//  - update b32 reads: bank = (4*oct + u) mod 32, all 32 lanes distinct
//    per phase (800 = 25*32 strides vanish) -> CONFLICT-FREE.
//  - 100*4 = 400 == 0 mod 16: no f4 splits (R13).
#define GPAD 100

__global__
__attribute__((amdgpu_flat_work_group_size(TPB, TPB), amdgpu_waves_per_eu(4, 4)))
void sgd_filter(const float* __restrict__ sos_in,
                const float* __restrict__ target,
                float* __restrict__ out) {
    // 16 sections x 6 floats, PAIRED: [b0 a0 b1 a1 b2 a2] per section.
    __shared__ __align__(16) float sos[96];
    // 128 rows (row = 2*(tid>>4) + quad-parity, a 4-freq group); col =
    // coeff id 0..95 = sec*6 + [b0,b1,b2,a0,a1,a2].
    __shared__ __align__(16) float gpart[128][GPAD];

    const int tid = threadIdx.x;
    const int qd  = tid >> 2;      // freq group: freqs 2qd, 2qd+1
    const int pos = tid & 3;       // section group: 4*pos .. 4*pos+3
    const float* secbase = &sos[pos * 24];

    if (tid < 96) sos[(tid / 6) * 6 + cmap(tid % 6)] = sos_in[tid];

    // Update identity: 8 threads per coefficient u = tid>>3 (tid<768).
    const int u    = tid >> 3;
    const int oct  = tid & 7;
    const int usec = u / 6, uk = u % 6;
    const int uscol = usec * 6 + cmap(uk);    // sos col (paired layout)
    const bool upd = (tid < 768);
    const bool writer = upd && (oct == 7);
    float myc = 0.0f;
    if (writer) myc = sos_in[u];
    const float* urp = &gpart[oct][0] + u;    // rows oct+8j (j=0..15), col u

    // Per-thread frequency constants (two freqs)
    const double step = 3.14159265358979323846 / 511.0;
    const float w0 = (float)((double)(2 * qd) * step);
    const float w1 = (float)((double)(2 * qd + 1) * step);
    const float c10 = cosf(w0), s10 = -sinf(w0);
    const float c20 = c10 * c10 - s10 * s10, s20 = 2.0f * c10 * s10;
    const float c11 = cosf(w1), s11 = -sinf(w1);
    const float c21 = c11 * c11 - s11 * s11, s21 = 2.0f * c11 * s11;
    const float2 tg = *(const float2*)&target[2 * qd];
    const float KC = 40.0f / (512.0f * 2.302585092994046f); // 40/(n*ln10)

    const v2f c1v0 = mk2(c10, c10), s1v0 = mk2(s10, s10);
    const v2f c2v0 = mk2(c20, c20), s2v0 = mk2(s20, s20);
    const v2f c1v1 = mk2(c11, c11), s1v1 = mk2(s11, s11);
    const v2f c2v1 = mk2(c21, c21), s2v1 = mk2(s21, s21);

    __syncthreads();

    // 4 sections x 2 freqs: Re, Im, n, then batched inverses V.
    v2f RA0, RA1, RA2, RA3, IA0, IA1, IA2, IA3, VA0, VA1, VA2, VA3;
    v2f RB0, RB1, RB2, RB3, IB0, IB1, IB2, IB3, VB0, VB1, VB2, VB3;
    v2f NA0, NA1, NA2, NA3, NB0, NB1, NB2, NB3;

// One section, BOTH freqs (coefficient pair regs shared). n kept; no rcp.
#define SEC_EVAL(sl, BA0, BA1, BA2)                                         \
    {                                                                       \
        const v2f ba0 = BA0, ba1 = BA1, ba2 = BA2;                          \
        RA##sl = fma2(ba2, c2v0, fma2(ba1, c1v0, ba0));                     \
        IA##sl = fma2(ba2, s2v0, ba1 * s1v0);                               \
        NA##sl = fma2(RA##sl, RA##sl, IA##sl * IA##sl);                     \
        RB##sl = fma2(ba2, c2v1, fma2(ba1, c1v1, ba0));                     \
        IB##sl = fma2(ba2, s2v1, ba1 * s1v1);                               \
        NB##sl = fma2(RB##sl, RB##sl, IB##sl * IB##sl);                     \
    }

// Backward: per section, per-freq (P,Q) then freq-pair combine, then ONE
// stride-8 DPP per value. Writers = lanes (tid&15)>=8; store row =
// 2*(tid>>4) + quad-parity; cols 24*pos + 6*sl. 2-way banks (free).
#define SEC_BWD(sl)                                                         \
    {                                                                       \
        const v2f KA = KK0 * VA##sl;                                        \
        const v2f PA = KA * RA##sl;                                         \
        const v2f QA = KA * IA##sl;                                         \
        const v2f KB = KK1 * VB##sl;                                        \
        const v2f PB = KB * RB##sl;                                         \
        const v2f QB = KB * IB##sl;                                         \
        const v2f P  = PA + PB;                                             \
        const v2f G1 = fma2(c1v0, PA, s1v0 * QA) + fma2(c1v1, PB, s1v1 * QB);\
        const v2f G2 = fma2(c2v0, PA, s2v0 * QA) + fma2(c2v1, PB, s2v1 * QB);\
        float g0, g1, g2, g3, g4, g5;                                       \
        red6_s8(P.x, G1.x, G2.x, P.y, G1.y, G2.y,                           \
                g0, g1, g2, g3, g4, g5);                                    \
        if ((tid & 15) >= 8) {                                              \
            float* p = &gpart[((tid >> 4) << 1) | ((tid >> 2) & 1)]         \
                             [24 * pos + 6 * (sl)];                         \
            *(float4*)p       = make_float4(g0, g1, g2, g3);                \
            *(float2*)(p + 4) = make_float2(g4, g5);                        \
        }                                                                   \
    }

    for (int it = 0; it < 1000; ++it) {
        // ---- forward: 6 b128 loads cover my 4 sections (broadcast,
        //      conflict-free); evaluate both freqs ----
        const float4 q0 = *(const float4*)(secbase + 0);
        const float4 q1 = *(const float4*)(secbase + 4);
        const float4 q2 = *(const float4*)(secbase + 8);
        const float4 q3 = *(const float4*)(secbase + 12);
        const float4 q4 = *(const float4*)(secbase + 16);
        const float4 q5 = *(const float4*)(secbase + 20);
        SEC_EVAL(0, mk2(q0.x, q0.y), mk2(q0.z, q0.w), mk2(q1.x, q1.y))
        SEC_EVAL(1, mk2(q1.z, q1.w), mk2(q2.x, q2.y), mk2(q2.z, q2.w))
        SEC_EVAL(2, mk2(q3.x, q3.y), mk2(q3.z, q3.w), mk2(q4.x, q4.y))
        SEC_EVAL(3, mk2(q4.z, q4.w), mk2(q5.x, q5.y), mk2(q5.z, q5.w))

        // ---- batched inverses (R6): one rcp2 per freq serves 4 sections.
        //      m = n0*n1*n2*n3 doubles as the L-product. ----
        const v2f tA01 = NA0 * NA1, tA23 = NA2 * NA3;
        const v2f mA   = tA01 * tA23;
        const v2f iA   = rcp2(mA);
        const v2f iA01 = iA * tA23, iA23 = iA * tA01;
        VA0 = iA01 * NA1; VA1 = iA01 * NA0;
        VA2 = iA23 * NA3; VA3 = iA23 * NA2;
        const v2f tB01 = NB0 * NB1, tB23 = NB2 * NB3;
        const v2f mB   = tB01 * tB23;
        const v2f iB   = rcp2(mB);
        const v2f iB01 = iB * tB23, iB23 = iB * tB01;
        VB0 = iB01 * NB1; VB1 = iB01 * NB0;
        VB2 = iB23 * NB3; VB3 = iB23 * NB2;

        float L0 = __builtin_amdgcn_logf(mA.x) - __builtin_amdgcn_logf(mA.y);
        float L1 = __builtin_amdgcn_logf(mB.x) - __builtin_amdgcn_logf(mB.y);

        // Quad butterfly: every lane gets the bit-identical 16-section total
        // for both of its freqs.
        quad_allsum2(L0, L1);

        const float mag0   = __builtin_amdgcn_exp2f(0.5f * L0);
        const float magpe0 = mag0 + 1e-8f;
        const float indB0  = 6.020599913279624f * __builtin_amdgcn_logf(magpe0);
        const float K0 = KC * (indB0 - tg.x) * mag0 * __builtin_amdgcn_rcpf(magpe0);
        const float mag1   = __builtin_amdgcn_exp2f(0.5f * L1);
        const float magpe1 = mag1 + 1e-8f;
        const float indB1  = 6.020599913279624f * __builtin_amdgcn_logf(magpe1);
        const float K1 = KC * (indB1 - tg.y) * mag1 * __builtin_amdgcn_rcpf(magpe1);
        const v2f KK0 = mk2(K0, -K0);   // A-side gradient sign folded here
        const v2f KK1 = mk2(K1, -K1);

        // ---- backward: 4 sections, freq-pair add + 1-stage DPP, store ----
        SEC_BWD(0) SEC_BWD(1) SEC_BWD(2) SEC_BWD(3)
        __syncthreads();

        // ---- update: 8 threads/coeff, 16 rows each (stride 8 rows = 800
        //      floats), conflict-free banks, tree-sum, 3-step DPP ----
        if (upd) {
            const float r0  = urp[0],        r1  = urp[1 * 800];
            const float r2  = urp[2 * 800],  r3  = urp[3 * 800];
            const float r4  = urp[4 * 800],  r5  = urp[5 * 800];
            const float r6  = urp[6 * 800],  r7  = urp[7 * 800];
            const float r8  = urp[8 * 800],  r9  = urp[9 * 800];
            const float r10 = urp[10 * 800], r11 = urp[11 * 800];
            const float r12 = urp[12 * 800], r13 = urp[13 * 800];
            const float r14 = urp[14 * 800], r15 = urp[15 * 800];
            const float t0 = (r0 + r1) + (r2 + r3);
            const float t1 = (r4 + r5) + (r6 + r7);
            const float t2 = (r8 + r9) + (r10 + r11);
            const float t3 = (r12 + r13) + (r14 + r15);
            float g = red1_g8((t0 + t1) + (t2 + t3));
            if (writer) {
                myc = fmaf(-0.1f, g, myc);
                sos[uscol] = myc;
            }
        }
        __syncthreads();
    }

    if (writer) out[u] = myc;
}

extern "C" void kernel_launch(void* const* d_in, const int* in_sizes, int n_in,
                              void* d_out, int out_size, void* d_ws, size_t ws_size,
                              hipStream_t stream) {
    const float* sos_in = (const float*)d_in[0];
    const float* target = (const float*)d_in[1];
    float* outp = (float*)d_out;
    hipLaunchKernelGGL(sgd_filter, dim3(1), dim3(TPB), 0, stream, sos_in, target, outp);
}